// Round 4
// baseline (445.950 us; speedup 1.0000x reference)
//
#include <hip/hip_runtime.h>
#include <hip/hip_bf16.h>

typedef __bf16 bf16x8 __attribute__((ext_vector_type(8)));
typedef float f32x4 __attribute__((ext_vector_type(4)));

// Problem constants: B=2, S=2048, D=1024, H=16, HD=64
#define NB 2
#define NS 2048
#define ND 1024
#define NH 16
#define NHD 64

__device__ __forceinline__ unsigned short f2b(float f) {
    union { __hip_bfloat16 h; unsigned short u; } c;
    c.h = __float2bfloat16(f);
    return c.u;
}

__device__ __forceinline__ void cvt16(const float4& v0, const float4& v1,
                                      const float4& v2, const float4& v3,
                                      unsigned short* dst) {
    alignas(16) unsigned short t[16];
    t[0] = f2b(v0.x); t[1] = f2b(v0.y); t[2]  = f2b(v0.z); t[3]  = f2b(v0.w);
    t[4] = f2b(v1.x); t[5] = f2b(v1.y); t[6]  = f2b(v1.z); t[7]  = f2b(v1.w);
    t[8] = f2b(v2.x); t[9] = f2b(v2.y); t[10] = f2b(v2.z); t[11] = f2b(v2.w);
    t[12] = f2b(v3.x); t[13] = f2b(v3.y); t[14] = f2b(v3.z); t[15] = f2b(v3.w);
    *(uint4*)dst = *(const uint4*)&t[0];
    *((uint4*)dst + 1) = *(const uint4*)&t[8];
}

// ---------------------------------------------------------------------------
// Mask dtype probe. flag = 1 -> 4-byte elements, 0 -> 1-byte.
// ---------------------------------------------------------------------------
__global__ void detect_mask(const unsigned* __restrict__ m, int* __restrict__ flag) {
    __shared__ int bad;
    if (threadIdx.x == 0) bad = 0;
    __syncthreads();
    int mybad = 0;
    for (int i = threadIdx.x; i < 8192; i += 256) {
        unsigned w = m[i];
        if (w != 0u && w != 1u && w != 0x3F800000u) mybad = 1;
    }
    if (mybad) bad = 1;
    __syncthreads();
    if (threadIdx.x == 0) *flag = bad ? 0 : 1;
}

// ---------------------------------------------------------------------------
// Bit-pack the mask: B*S*S elements -> u64 words (1 MB, L2-resident).
// ---------------------------------------------------------------------------
__global__ __launch_bounds__(256) void pack_mask(
    const void* __restrict__ mask, const int* __restrict__ mflag,
    unsigned long long* __restrict__ mbits)
{
    const int wave = threadIdx.x >> 6;
    const int lane = threadIdx.x & 63;
    const size_t w = (size_t)blockIdx.x * 4 + wave;
    const size_t e = w * 64 + lane;
    int v;
    if (*mflag) v = (((const unsigned*)mask)[e] != 0u);
    else        v = (((const unsigned char*)mask)[e] != 0);
    unsigned long long bits = __ballot(v);
    if (lane == 0) mbits[w] = bits;
}

// ---------------------------------------------------------------------------
// QKV projection (unchanged): y = x @ W.T + b
// Q,K stored [B,H,S,HD] bf16; V stored transposed [B,H,HD,S] bf16.
// ---------------------------------------------------------------------------
__global__ __launch_bounds__(256) void qkv_gemm(
    const float* __restrict__ x,
    const float* __restrict__ Wq, const float* __restrict__ bq,
    const float* __restrict__ Wk, const float* __restrict__ bk,
    const float* __restrict__ Wv, const float* __restrict__ bv,
    unsigned short* __restrict__ Qb, unsigned short* __restrict__ Kb,
    unsigned short* __restrict__ Vtb)
{
    __shared__ alignas(16) unsigned short Alds[128][32];
    __shared__ alignas(16) unsigned short Blds[128][32];

    const int tid  = threadIdx.x;
    const int wave = tid >> 6;
    const int lane = tid & 63;
    const int z    = blockIdx.z;

    const float* W    = (z == 0) ? Wq : (z == 1) ? Wk : Wv;
    const float* bias = (z == 0) ? bq : (z == 1) ? bk : bv;

    const int m0 = blockIdx.x * 128;
    const int n0 = blockIdx.y * 128;
    const int wr = (wave >> 1) * 64;
    const int wc = (wave & 1) * 64;

    const int srow = tid >> 1;
    const int scol = (tid & 1) * 16;
    const float* xsrc = x + (size_t)(m0 + srow) * ND + scol;
    const float* wsrc = W + (size_t)(n0 + srow) * ND + scol;

    const int lg = lane >> 4;
    const int ll = lane & 15;
    const int kcol = lg * 8;

    f32x4 acc[4][4] = {};

    for (int kt = 0; kt < ND; kt += 32) {
        float4 a0 = *(const float4*)(xsrc + kt);
        float4 a1 = *(const float4*)(xsrc + kt + 4);
        float4 a2 = *(const float4*)(xsrc + kt + 8);
        float4 a3 = *(const float4*)(xsrc + kt + 12);
        float4 b0 = *(const float4*)(wsrc + kt);
        float4 b1 = *(const float4*)(wsrc + kt + 4);
        float4 b2 = *(const float4*)(wsrc + kt + 8);
        float4 b3 = *(const float4*)(wsrc + kt + 12);

        if (kt != 0) __syncthreads();
        cvt16(a0, a1, a2, a3, &Alds[srow][scol]);
        cvt16(b0, b1, b2, b3, &Blds[srow][scol]);
        __syncthreads();

        bf16x8 af[4], bfr[4];
        #pragma unroll
        for (int m = 0; m < 4; m++)
            af[m] = *(const bf16x8*)&Alds[wr + m * 16 + ll][kcol];
        #pragma unroll
        for (int n = 0; n < 4; n++)
            bfr[n] = *(const bf16x8*)&Blds[wc + n * 16 + ll][kcol];

        #pragma unroll
        for (int m = 0; m < 4; m++)
            #pragma unroll
            for (int n = 0; n < 4; n++)
                acc[m][n] = __builtin_amdgcn_mfma_f32_16x16x32_bf16(
                    af[m], bfr[n], acc[m][n], 0, 0, 0);
    }

    #pragma unroll
    for (int n = 0; n < 4; n++) {
        const int j  = n0 + wc + n * 16 + ll;
        const float bj = bias[j];
        const int hh = j >> 6;
        const int hd = j & 63;
        #pragma unroll
        for (int m = 0; m < 4; m++) {
            #pragma unroll
            for (int r = 0; r < 4; r++) {
                const int i  = m0 + wr + m * 16 + lg * 4 + r;
                const int bb = i >> 11;
                const int ss = i & 2047;
                const unsigned short o = f2b(acc[m][n][r] + bj);
                if (z == 2) {
                    Vtb[((size_t)(bb * NH + hh) * NHD + hd) * NS + ss] = o;
                } else {
                    const size_t idx = ((size_t)(bb * NH + hh) * NS + ss) * NHD + hd;
                    if (z == 0) Qb[idx] = o; else Kb[idx] = o;
                }
            }
        }
    }
}

// ---------------------------------------------------------------------------
// Flash attention, split-K capable. One wave per 16 q-rows per key-split.
// nsplit==1: write normalized out directly (round-3 behavior).
// nsplit==2: write unnormalized O + (m,l) partials for the combine kernel.
// ---------------------------------------------------------------------------
__global__ __launch_bounds__(256) void attn_kernel(
    const unsigned short* __restrict__ Qb, const unsigned short* __restrict__ Kb,
    const unsigned short* __restrict__ Vtb,
    const unsigned long long* __restrict__ mbits,
    float* __restrict__ Opart, float2* __restrict__ ML,
    float* __restrict__ out, int nsplit)
{
    __shared__ alignas(16) unsigned short Plds[4][16][72];

    const int tid  = threadIdx.x;
    const int wave = tid >> 6;
    const int lane = tid & 63;
    const int b     = blockIdx.z / nsplit;
    const int split = blockIdx.z % nsplit;
    const int klen  = NS / nsplit;
    const int koff  = split * klen;
    const int h = blockIdx.y;
    const int q0 = blockIdx.x * 64 + wave * 16;

    const unsigned short* Qp = Qb  + (size_t)(b * NH + h) * NS * NHD;
    const unsigned short* Kp = Kb  + (size_t)(b * NH + h) * NS * NHD;
    const unsigned short* Vp = Vtb + (size_t)(b * NH + h) * NHD * NS;
    const unsigned long long* mrow = mbits + (size_t)b * NS * (NS / 64);

    const int lg = lane >> 4;
    const int ll = lane & 15;
    const int kcol = lg * 8;

    const bf16x8 qf0 = *(const bf16x8*)&Qp[(q0 + ll) * NHD + kcol];
    const bf16x8 qf1 = *(const bf16x8*)&Qp[(q0 + ll) * NHD + 32 + kcol];

    f32x4 O0 = {}, O1 = {}, O2 = {}, O3 = {};
    float mrun[4] = {-3.0e38f, -3.0e38f, -3.0e38f, -3.0e38f};
    float lrun[4] = {0.f, 0.f, 0.f, 0.f};

    const float scale = 0.03125f;  // 1/sqrt(1024)

    for (int kb = koff; kb < koff + klen; kb += 64) {
        // ---- QK^T: four 16-key tiles ----
        f32x4 s0 = {}, s1 = {}, s2 = {}, s3 = {};
        {
            bf16x8 a = *(const bf16x8*)&Kp[(kb + ll) * NHD + kcol];
            bf16x8 c = *(const bf16x8*)&Kp[(kb + ll) * NHD + 32 + kcol];
            s0 = __builtin_amdgcn_mfma_f32_16x16x32_bf16(qf0, a, s0, 0, 0, 0);
            s0 = __builtin_amdgcn_mfma_f32_16x16x32_bf16(qf1, c, s0, 0, 0, 0);
        }
        {
            bf16x8 a = *(const bf16x8*)&Kp[(kb + 16 + ll) * NHD + kcol];
            bf16x8 c = *(const bf16x8*)&Kp[(kb + 16 + ll) * NHD + 32 + kcol];
            s1 = __builtin_amdgcn_mfma_f32_16x16x32_bf16(qf0, a, s1, 0, 0, 0);
            s1 = __builtin_amdgcn_mfma_f32_16x16x32_bf16(qf1, c, s1, 0, 0, 0);
        }
        {
            bf16x8 a = *(const bf16x8*)&Kp[(kb + 32 + ll) * NHD + kcol];
            bf16x8 c = *(const bf16x8*)&Kp[(kb + 32 + ll) * NHD + 32 + kcol];
            s2 = __builtin_amdgcn_mfma_f32_16x16x32_bf16(qf0, a, s2, 0, 0, 0);
            s2 = __builtin_amdgcn_mfma_f32_16x16x32_bf16(qf1, c, s2, 0, 0, 0);
        }
        {
            bf16x8 a = *(const bf16x8*)&Kp[(kb + 48 + ll) * NHD + kcol];
            bf16x8 c = *(const bf16x8*)&Kp[(kb + 48 + ll) * NHD + 32 + kcol];
            s3 = __builtin_amdgcn_mfma_f32_16x16x32_bf16(qf0, a, s3, 0, 0, 0);
            s3 = __builtin_amdgcn_mfma_f32_16x16x32_bf16(qf1, c, s3, 0, 0, 0);
        }

        unsigned long long mw[4];
        #pragma unroll
        for (int r = 0; r < 4; r++)
            mw[r] = mrow[(size_t)(q0 + lg * 4 + r) * (NS / 64) + (kb >> 6)];

        #pragma unroll
        for (int r = 0; r < 4; r++) {
            const unsigned lo = (unsigned)mw[r];
            const unsigned hi = (unsigned)(mw[r] >> 32);
            float sv0 = ((lo >> ll)        & 1u) ? -1e9f : s0[r] * scale;
            float sv1 = ((lo >> (16 + ll)) & 1u) ? -1e9f : s1[r] * scale;
            float sv2 = ((hi >> ll)        & 1u) ? -1e9f : s2[r] * scale;
            float sv3 = ((hi >> (16 + ll)) & 1u) ? -1e9f : s3[r] * scale;

            float mt = fmaxf(fmaxf(sv0, sv1), fmaxf(sv2, sv3));
            mt = fmaxf(mt, __shfl_xor(mt, 1));
            mt = fmaxf(mt, __shfl_xor(mt, 2));
            mt = fmaxf(mt, __shfl_xor(mt, 4));
            mt = fmaxf(mt, __shfl_xor(mt, 8));

            const float mnew  = fmaxf(mrun[r], mt);
            const float alpha = __expf(mrun[r] - mnew);
            const float p0 = __expf(sv0 - mnew);
            const float p1 = __expf(sv1 - mnew);
            const float p2 = __expf(sv2 - mnew);
            const float p3 = __expf(sv3 - mnew);

            float rs = (p0 + p1) + (p2 + p3);
            rs += __shfl_xor(rs, 1);
            rs += __shfl_xor(rs, 2);
            rs += __shfl_xor(rs, 4);
            rs += __shfl_xor(rs, 8);

            lrun[r] = lrun[r] * alpha + rs;
            mrun[r] = mnew;
            O0[r] *= alpha; O1[r] *= alpha; O2[r] *= alpha; O3[r] *= alpha;

            const int prow = lg * 4 + r;
            Plds[wave][prow][ll]      = f2b(p0);
            Plds[wave][prow][16 + ll] = f2b(p1);
            Plds[wave][prow][32 + ll] = f2b(p2);
            Plds[wave][prow][48 + ll] = f2b(p3);
        }

        const bf16x8 pa0 = *(const bf16x8*)&Plds[wave][ll][kcol];
        const bf16x8 pa1 = *(const bf16x8*)&Plds[wave][ll][32 + kcol];
        #pragma unroll
        for (int d = 0; d < 4; d++) {
            const bf16x8 v0 = *(const bf16x8*)&Vp[(size_t)(d * 16 + ll) * NS + kb + kcol];
            const bf16x8 v1 = *(const bf16x8*)&Vp[(size_t)(d * 16 + ll) * NS + kb + 32 + kcol];
            f32x4& Od = (d == 0) ? O0 : (d == 1) ? O1 : (d == 2) ? O2 : O3;
            Od = __builtin_amdgcn_mfma_f32_16x16x32_bf16(pa0, v0, Od, 0, 0, 0);
            Od = __builtin_amdgcn_mfma_f32_16x16x32_bf16(pa1, v1, Od, 0, 0, 0);
        }
    }

    if (nsplit == 1) {
        #pragma unroll
        for (int r = 0; r < 4; r++) {
            const int q = q0 + lg * 4 + r;
            const float inv = 1.0f / lrun[r];
            float* op = out + (size_t)(b * NS + q) * ND + h * NHD;
            op[0 * 16 + ll] = O0[r] * inv;
            op[1 * 16 + ll] = O1[r] * inv;
            op[2 * 16 + ll] = O2[r] * inv;
            op[3 * 16 + ll] = O3[r] * inv;
        }
    } else {
        #pragma unroll
        for (int r = 0; r < 4; r++) {
            const int q = q0 + lg * 4 + r;
            const size_t row = ((size_t)(split * NB + b) * NH + h) * NS + q;
            float* op = Opart + row * NHD;
            op[0 * 16 + ll] = O0[r];
            op[1 * 16 + ll] = O1[r];
            op[2 * 16 + ll] = O2[r];
            op[3 * 16 + ll] = O3[r];
            if (ll == 0) ML[row] = make_float2(mrun[r], lrun[r]);
        }
    }
}

// ---------------------------------------------------------------------------
// Split-K combine: out = (O0*e^{m0-m} + O1*e^{m1-m}) / (l0*e^{m0-m} + l1*e^{m1-m})
// One thread per output element; block covers 4 q-rows x 64 d for one (b,h).
// ---------------------------------------------------------------------------
__global__ __launch_bounds__(256) void combine2(
    const float* __restrict__ Opart, const float2* __restrict__ ML,
    float* __restrict__ out)
{
    const int d  = threadIdx.x & 63;
    const int qi = threadIdx.x >> 6;
    const int q = blockIdx.x * 4 + qi;
    const int h = blockIdx.y;
    const int b = blockIdx.z;

    const size_t r0 = ((size_t)(0 * NB + b) * NH + h) * NS + q;
    const size_t r1 = ((size_t)(1 * NB + b) * NH + h) * NS + q;
    const float2 ml0 = ML[r0];
    const float2 ml1 = ML[r1];
    const float m  = fmaxf(ml0.x, ml1.x);
    const float w0 = __expf(ml0.x - m);
    const float w1 = __expf(ml1.x - m);
    const float l  = ml0.y * w0 + ml1.y * w1;
    const float o  = (Opart[r0 * NHD + d] * w0 + Opart[r1 * NHD + d] * w1) / l;
    out[(size_t)(b * NS + q) * ND + h * NHD + d] = o;
}

extern "C" void kernel_launch(void* const* d_in, const int* in_sizes, int n_in,
                              void* d_out, int out_size, void* d_ws, size_t ws_size,
                              hipStream_t stream)
{
    const float* x  = (const float*)d_in[0];
    const void* mask = d_in[1];
    const float* Wq = (const float*)d_in[2];
    const float* bq = (const float*)d_in[3];
    const float* Wk = (const float*)d_in[4];
    const float* bk = (const float*)d_in[5];
    const float* Wv = (const float*)d_in[6];
    const float* bv = (const float*)d_in[7];
    float* out = (float*)d_out;

    const size_t szQ = (size_t)NB * NH * NS * NHD;        // 4M elements
    const size_t nWords = (size_t)NB * NS * (NS / 64);    // 128K u64

    int* mflag = (int*)d_ws;
    unsigned short* Qb  = (unsigned short*)((char*)d_ws + 256);
    unsigned short* Kb  = Qb + szQ;
    unsigned short* Vtb = Kb + szQ;
    unsigned long long* mbits = (unsigned long long*)(Vtb + szQ);
    float*  Opart = (float*)(mbits + nWords);
    float2* ML    = (float2*)(Opart + 2 * szQ);

    const size_t need = 256 + 3 * szQ * 2 + nWords * 8    // base (25.3 MB)
                      + 2 * szQ * 4 + (size_t)2 * NB * NH * NS * 8;  // +33.5 MB
    const int nsplit = (ws_size >= need) ? 2 : 1;

    dim3 blk(256);
    detect_mask<<<dim3(1), blk, 0, stream>>>((const unsigned*)mask, mflag);

    const int words = NB * NS * NS / 64;
    pack_mask<<<dim3(words / 4), blk, 0, stream>>>(mask, mflag, mbits);

    dim3 g1(32, 8, 3);
    qkv_gemm<<<g1, blk, 0, stream>>>(x, Wq, bq, Wk, bk, Wv, bv, Qb, Kb, Vtb);

    dim3 g2(NS / 64, NH, NB * nsplit);
    attn_kernel<<<g2, blk, 0, stream>>>(Qb, Kb, Vtb, mbits, Opart, ML, out, nsplit);

    if (nsplit == 2) {
        dim3 g3(NS / 4, NH, NB);
        combine2<<<g3, blk, 0, stream>>>(Opart, ML, out);
    }
}

// Round 5
// 418.315 us; speedup vs baseline: 1.0661x; 1.0661x over previous
//
#include <hip/hip_runtime.h>
#include <hip/hip_bf16.h>

typedef __bf16 bf16x8 __attribute__((ext_vector_type(8)));
typedef float f32x4 __attribute__((ext_vector_type(4)));

// Problem constants: B=2, S=2048, D=1024, H=16, HD=64
#define NB 2
#define NS 2048
#define ND 1024
#define NH 16
#define NHD 64

__device__ __forceinline__ unsigned short f2b(float f) {
    union { __hip_bfloat16 h; unsigned short u; } c;
    c.h = __float2bfloat16(f);
    return c.u;
}

// ---------------------------------------------------------------------------
// f32 -> bf16 bulk convert (vectorized, 8 elems/thread)
// ---------------------------------------------------------------------------
__global__ __launch_bounds__(256) void to_bf16(
    const float* __restrict__ src, unsigned short* __restrict__ dst, int n)
{
    for (int i = ((int)blockIdx.x * 256 + (int)threadIdx.x) * 8; i < n;
         i += (int)gridDim.x * 256 * 8) {
        float4 a = *(const float4*)(src + i);
        float4 b = *(const float4*)(src + i + 4);
        alignas(16) unsigned short t[8];
        t[0] = f2b(a.x); t[1] = f2b(a.y); t[2] = f2b(a.z); t[3] = f2b(a.w);
        t[4] = f2b(b.x); t[5] = f2b(b.y); t[6] = f2b(b.z); t[7] = f2b(b.w);
        *(uint4*)(dst + i) = *(const uint4*)t;
    }
}

// ---------------------------------------------------------------------------
// Mask dtype probe. flag = 1 -> 4-byte elements, 0 -> 1-byte.
// ---------------------------------------------------------------------------
__global__ void detect_mask(const unsigned* __restrict__ m, int* __restrict__ flag) {
    __shared__ int bad;
    if (threadIdx.x == 0) bad = 0;
    __syncthreads();
    int mybad = 0;
    for (int i = threadIdx.x; i < 8192; i += 256) {
        unsigned w = m[i];
        if (w != 0u && w != 1u && w != 0x3F800000u) mybad = 1;
    }
    if (mybad) bad = 1;
    __syncthreads();
    if (threadIdx.x == 0) *flag = bad ? 0 : 1;
}

// ---------------------------------------------------------------------------
// Bit-pack the mask: B*S*S elements -> u64 words (1 MB, L2-resident).
// ---------------------------------------------------------------------------
__global__ __launch_bounds__(256) void pack_mask(
    const void* __restrict__ mask, const int* __restrict__ mflag,
    unsigned long long* __restrict__ mbits)
{
    const int wave = threadIdx.x >> 6;
    const int lane = threadIdx.x & 63;
    const size_t w = (size_t)blockIdx.x * 4 + wave;
    const size_t e = w * 64 + lane;
    int v;
    if (*mflag) v = (((const unsigned*)mask)[e] != 0u);
    else        v = (((const unsigned char*)mask)[e] != 0);
    unsigned long long bits = __ballot(v);
    if (lane == 0) mbits[w] = bits;
}

// ---------------------------------------------------------------------------
// QKV projection from pre-converted bf16 x / W: y = x @ W.T + b
// Q,K stored [B,H,S,HD] bf16; V stored transposed [B,H,HD,S] bf16.
// 128x128 tile, 4 waves, BK=32; LDS rows padded to 40 shorts (2-way banks).
// ---------------------------------------------------------------------------
__global__ __launch_bounds__(256) void qkv_gemm(
    const unsigned short* __restrict__ xb,
    const unsigned short* __restrict__ Wqb, const float* __restrict__ bq,
    const unsigned short* __restrict__ Wkb, const float* __restrict__ bk,
    const unsigned short* __restrict__ Wvb, const float* __restrict__ bv,
    unsigned short* __restrict__ Qb, unsigned short* __restrict__ Kb,
    unsigned short* __restrict__ Vtb)
{
    __shared__ alignas(16) unsigned short Alds[128][40];
    __shared__ alignas(16) unsigned short Blds[128][40];

    const int tid  = threadIdx.x;
    const int wave = tid >> 6;
    const int lane = tid & 63;
    const int z    = blockIdx.z;

    const unsigned short* W = (z == 0) ? Wqb : (z == 1) ? Wkb : Wvb;
    const float* bias       = (z == 0) ? bq  : (z == 1) ? bk  : bv;

    const int m0 = blockIdx.x * 128;
    const int n0 = blockIdx.y * 128;
    const int wr = (wave >> 1) * 64;
    const int wc = (wave & 1) * 64;

    const int srow = tid >> 1;
    const int scol = (tid & 1) * 16;
    const unsigned short* xsrc = xb + (size_t)(m0 + srow) * ND + scol;
    const unsigned short* wsrc = W  + (size_t)(n0 + srow) * ND + scol;

    const int lg = lane >> 4;
    const int ll = lane & 15;
    const int kcol = lg * 8;

    f32x4 acc[4][4] = {};

    for (int kt = 0; kt < ND; kt += 32) {
        uint4 a0 = *(const uint4*)(xsrc + kt);
        uint4 a1 = *(const uint4*)(xsrc + kt + 8);
        uint4 b0 = *(const uint4*)(wsrc + kt);
        uint4 b1 = *(const uint4*)(wsrc + kt + 8);

        if (kt != 0) __syncthreads();
        *(uint4*)&Alds[srow][scol]     = a0;
        *(uint4*)&Alds[srow][scol + 8] = a1;
        *(uint4*)&Blds[srow][scol]     = b0;
        *(uint4*)&Blds[srow][scol + 8] = b1;
        __syncthreads();

        bf16x8 af[4], bfr[4];
        #pragma unroll
        for (int m = 0; m < 4; m++)
            af[m] = *(const bf16x8*)&Alds[wr + m * 16 + ll][kcol];
        #pragma unroll
        for (int n = 0; n < 4; n++)
            bfr[n] = *(const bf16x8*)&Blds[wc + n * 16 + ll][kcol];

        __builtin_amdgcn_s_setprio(1);
        #pragma unroll
        for (int m = 0; m < 4; m++)
            #pragma unroll
            for (int n = 0; n < 4; n++)
                acc[m][n] = __builtin_amdgcn_mfma_f32_16x16x32_bf16(
                    af[m], bfr[n], acc[m][n], 0, 0, 0);
        __builtin_amdgcn_s_setprio(0);
    }

    #pragma unroll
    for (int n = 0; n < 4; n++) {
        const int j  = n0 + wc + n * 16 + ll;
        const float bj = bias[j];
        const int hh = j >> 6;
        const int hd = j & 63;
        #pragma unroll
        for (int m = 0; m < 4; m++) {
            #pragma unroll
            for (int r = 0; r < 4; r++) {
                const int i  = m0 + wr + m * 16 + lg * 4 + r;
                const int bb = i >> 11;
                const int ss = i & 2047;
                const unsigned short o = f2b(acc[m][n][r] + bj);
                if (z == 2) {
                    Vtb[((size_t)(bb * NH + hh) * NHD + hd) * NS + ss] = o;
                } else {
                    const size_t idx = ((size_t)(bb * NH + hh) * NS + ss) * NHD + hd;
                    if (z == 0) Qb[idx] = o; else Kb[idx] = o;
                }
            }
        }
    }
}

// ---------------------------------------------------------------------------
// Flash attention, swapped-QK^T softmax: s = mfma(K, Q) puts all 64 keys of a
// chunk for q-row (lane&15) IN-LANE (16 values) -> row reduce = in-lane tree
// + 2 shfl_xor. Mask = 1 u64 word/lane. Defer-max skips O-rescale when the
// running max doesn't grow (T13). PV unchanged (P via small LDS tile).
// ---------------------------------------------------------------------------
__global__ __launch_bounds__(256) void attn_kernel(
    const unsigned short* __restrict__ Qb, const unsigned short* __restrict__ Kb,
    const unsigned short* __restrict__ Vtb,
    const unsigned long long* __restrict__ mbits, float* __restrict__ out)
{
    __shared__ alignas(16) unsigned short Plds[4][16][72];

    const int tid  = threadIdx.x;
    const int wave = tid >> 6;
    const int lane = tid & 63;
    const int b = blockIdx.z;
    const int h = blockIdx.y;
    const int q0 = blockIdx.x * 64 + wave * 16;

    const unsigned short* Qp = Qb  + (size_t)(b * NH + h) * NS * NHD;
    const unsigned short* Kp = Kb  + (size_t)(b * NH + h) * NS * NHD;
    const unsigned short* Vp = Vtb + (size_t)(b * NH + h) * NHD * NS;
    const unsigned long long* mrow = mbits + (size_t)b * NS * (NS / 64);

    const int lg = lane >> 4;
    const int ll = lane & 15;
    const int kcol = lg * 8;

    // Q fragments (B-operand now; same addresses as before)
    const bf16x8 qf0 = *(const bf16x8*)&Qp[(q0 + ll) * NHD + kcol];
    const bf16x8 qf1 = *(const bf16x8*)&Qp[(q0 + ll) * NHD + 32 + kcol];

    f32x4 O0 = {}, O1 = {}, O2 = {}, O3 = {};
    float mrun = -3.0e38f;   // running max for q = q0 + ll (replicated per lg)
    float lrun = 0.f;        // running denom for q = q0 + ll

    const float scale = 0.03125f;  // 1/sqrt(1024)

    for (int kb = 0; kb < NS; kb += 64) {
        // ---- issue all loads early: K A-frags, mask word, V B-frags ----
        bf16x8 k00 = *(const bf16x8*)&Kp[(kb      + ll) * NHD + kcol];
        bf16x8 k01 = *(const bf16x8*)&Kp[(kb      + ll) * NHD + 32 + kcol];
        bf16x8 k10 = *(const bf16x8*)&Kp[(kb + 16 + ll) * NHD + kcol];
        bf16x8 k11 = *(const bf16x8*)&Kp[(kb + 16 + ll) * NHD + 32 + kcol];
        bf16x8 k20 = *(const bf16x8*)&Kp[(kb + 32 + ll) * NHD + kcol];
        bf16x8 k21 = *(const bf16x8*)&Kp[(kb + 32 + ll) * NHD + 32 + kcol];
        bf16x8 k30 = *(const bf16x8*)&Kp[(kb + 48 + ll) * NHD + kcol];
        bf16x8 k31 = *(const bf16x8*)&Kp[(kb + 48 + ll) * NHD + 32 + kcol];
        const unsigned long long mw = mrow[(size_t)(q0 + ll) * (NS / 64) + (kb >> 6)];

        // ---- QK^T swapped: out row = k-local (lg*4+r), col = q-local (ll) ----
        f32x4 s0 = {}, s1 = {}, s2 = {}, s3 = {};
        __builtin_amdgcn_s_setprio(1);
        s0 = __builtin_amdgcn_mfma_f32_16x16x32_bf16(k00, qf0, s0, 0, 0, 0);
        s1 = __builtin_amdgcn_mfma_f32_16x16x32_bf16(k10, qf0, s1, 0, 0, 0);
        s2 = __builtin_amdgcn_mfma_f32_16x16x32_bf16(k20, qf0, s2, 0, 0, 0);
        s3 = __builtin_amdgcn_mfma_f32_16x16x32_bf16(k30, qf0, s3, 0, 0, 0);
        s0 = __builtin_amdgcn_mfma_f32_16x16x32_bf16(k01, qf1, s0, 0, 0, 0);
        s1 = __builtin_amdgcn_mfma_f32_16x16x32_bf16(k11, qf1, s1, 0, 0, 0);
        s2 = __builtin_amdgcn_mfma_f32_16x16x32_bf16(k21, qf1, s2, 0, 0, 0);
        s3 = __builtin_amdgcn_mfma_f32_16x16x32_bf16(k31, qf1, s3, 0, 0, 0);
        __builtin_amdgcn_s_setprio(0);

        // V B-frags (independent; issue before softmax)
        bf16x8 v00 = *(const bf16x8*)&Vp[(size_t)(0 * 16 + ll) * NS + kb + kcol];
        bf16x8 v01 = *(const bf16x8*)&Vp[(size_t)(0 * 16 + ll) * NS + kb + 32 + kcol];
        bf16x8 v10 = *(const bf16x8*)&Vp[(size_t)(1 * 16 + ll) * NS + kb + kcol];
        bf16x8 v11 = *(const bf16x8*)&Vp[(size_t)(1 * 16 + ll) * NS + kb + 32 + kcol];
        bf16x8 v20 = *(const bf16x8*)&Vp[(size_t)(2 * 16 + ll) * NS + kb + kcol];
        bf16x8 v21 = *(const bf16x8*)&Vp[(size_t)(2 * 16 + ll) * NS + kb + 32 + kcol];
        bf16x8 v30 = *(const bf16x8*)&Vp[(size_t)(3 * 16 + ll) * NS + kb + kcol];
        bf16x8 v31 = *(const bf16x8*)&Vp[(size_t)(3 * 16 + ll) * NS + kb + 32 + kcol];

        // ---- scores for q = q0+ll: sv[t*4+r] = score(k = kb + 16t + 4lg + r) ----
        const unsigned long long mws = mw >> (lg * 4);
        float sv[16];
        #pragma unroll
        for (int t = 0; t < 4; t++) {
            const f32x4 st = (t == 0) ? s0 : (t == 1) ? s1 : (t == 2) ? s2 : s3;
            #pragma unroll
            for (int r = 0; r < 4; r++)
                sv[t * 4 + r] = ((mws >> (16 * t + r)) & 1ull) ? -1e9f
                                                               : st[r] * scale;
        }

        // ---- in-lane max tree + cross-lg ----
        float m01 = fmaxf(fmaxf(sv[0], sv[1]), fmaxf(sv[2], sv[3]));
        float m23 = fmaxf(fmaxf(sv[4], sv[5]), fmaxf(sv[6], sv[7]));
        float m45 = fmaxf(fmaxf(sv[8], sv[9]), fmaxf(sv[10], sv[11]));
        float m67 = fmaxf(fmaxf(sv[12], sv[13]), fmaxf(sv[14], sv[15]));
        float mt = fmaxf(fmaxf(m01, m23), fmaxf(m45, m67));
        mt = fmaxf(mt, __shfl_xor(mt, 16));
        mt = fmaxf(mt, __shfl_xor(mt, 32));

        // ---- defer-max: rescale only when running max grows materially ----
        if (!__all(mt <= mrun + 8.0f)) {
            const float mnew  = fmaxf(mrun, mt);
            const float alpha = __expf(mrun - mnew);
            mrun = mnew;
            lrun *= alpha;
            #pragma unroll
            for (int r = 0; r < 4; r++) {
                const float ar = __shfl(alpha, lg * 4 + r);
                O0[r] *= ar; O1[r] *= ar; O2[r] *= ar; O3[r] *= ar;
            }
        }

        // ---- exp + sum + pack P to bf16 ----
        float p[16];
        #pragma unroll
        for (int i = 0; i < 16; i++) p[i] = __expf(sv[i] - mrun);
        float rs = ((p[0] + p[1]) + (p[2] + p[3])) + ((p[4] + p[5]) + (p[6] + p[7]))
                 + ((p[8] + p[9]) + (p[10] + p[11])) + ((p[12] + p[13]) + (p[14] + p[15]));
        rs += __shfl_xor(rs, 16);
        rs += __shfl_xor(rs, 32);
        lrun += rs;

        #pragma unroll
        for (int t = 0; t < 4; t++) {
            uint2 w;
            w.x = (unsigned)f2b(p[t * 4 + 0]) | ((unsigned)f2b(p[t * 4 + 1]) << 16);
            w.y = (unsigned)f2b(p[t * 4 + 2]) | ((unsigned)f2b(p[t * 4 + 3]) << 16);
            *(uint2*)&Plds[wave][ll][t * 16 + lg * 4] = w;
        }

        // ---- PV: A = P[16q x 64k] (two 32-k halves), B = V^T fragments ----
        const bf16x8 pa0 = *(const bf16x8*)&Plds[wave][ll][kcol];
        const bf16x8 pa1 = *(const bf16x8*)&Plds[wave][ll][32 + kcol];
        __builtin_amdgcn_s_setprio(1);
        O0 = __builtin_amdgcn_mfma_f32_16x16x32_bf16(pa0, v00, O0, 0, 0, 0);
        O1 = __builtin_amdgcn_mfma_f32_16x16x32_bf16(pa0, v10, O1, 0, 0, 0);
        O2 = __builtin_amdgcn_mfma_f32_16x16x32_bf16(pa0, v20, O2, 0, 0, 0);
        O3 = __builtin_amdgcn_mfma_f32_16x16x32_bf16(pa0, v30, O3, 0, 0, 0);
        O0 = __builtin_amdgcn_mfma_f32_16x16x32_bf16(pa1, v01, O0, 0, 0, 0);
        O1 = __builtin_amdgcn_mfma_f32_16x16x32_bf16(pa1, v11, O1, 0, 0, 0);
        O2 = __builtin_amdgcn_mfma_f32_16x16x32_bf16(pa1, v21, O2, 0, 0, 0);
        O3 = __builtin_amdgcn_mfma_f32_16x16x32_bf16(pa1, v31, O3, 0, 0, 0);
        __builtin_amdgcn_s_setprio(0);
    }

    // ---- epilogue: normalize (lrun lives at lane q') and store f32 ----
    #pragma unroll
    for (int r = 0; r < 4; r++) {
        const int q = q0 + lg * 4 + r;
        const float inv = 1.0f / __shfl(lrun, lg * 4 + r);
        float* op = out + (size_t)(b * NS + q) * ND + h * NHD;
        op[0 * 16 + ll] = O0[r] * inv;
        op[1 * 16 + ll] = O1[r] * inv;
        op[2 * 16 + ll] = O2[r] * inv;
        op[3 * 16 + ll] = O3[r] * inv;
    }
}

extern "C" void kernel_launch(void* const* d_in, const int* in_sizes, int n_in,
                              void* d_out, int out_size, void* d_ws, size_t ws_size,
                              hipStream_t stream)
{
    const float* x  = (const float*)d_in[0];
    const void* mask = d_in[1];
    const float* Wq = (const float*)d_in[2];
    const float* bq = (const float*)d_in[3];
    const float* Wk = (const float*)d_in[4];
    const float* bk = (const float*)d_in[5];
    const float* Wv = (const float*)d_in[6];
    const float* bv = (const float*)d_in[7];
    float* out = (float*)d_out;

    const size_t szX = (size_t)NB * NS * ND;              // 4M elems
    const size_t szW = (size_t)ND * ND;                   // 1M elems
    const size_t szQ = (size_t)NB * NH * NS * NHD;        // 4M elems
    const size_t nWords = (size_t)NB * NS * (NS / 64);    // 128K u64

    int* mflag = (int*)d_ws;
    unsigned short* xb  = (unsigned short*)((char*)d_ws + 256);  // 8MB
    unsigned short* Wqb = xb  + szX;                             // 2MB
    unsigned short* Wkb = Wqb + szW;                             // 2MB
    unsigned short* Wvb = Wkb + szW;                             // 2MB
    unsigned short* Qb  = Wvb + szW;                             // 8MB
    unsigned short* Kb  = Qb + szQ;                              // 8MB
    unsigned short* Vtb = Kb + szQ;                              // 8MB
    unsigned long long* mbits = (unsigned long long*)(Vtb + szQ);// 1MB

    dim3 blk(256);
    to_bf16<<<dim3(2048), blk, 0, stream>>>(x,  xb,  (int)szX);
    to_bf16<<<dim3(512),  blk, 0, stream>>>(Wq, Wqb, (int)szW);
    to_bf16<<<dim3(512),  blk, 0, stream>>>(Wk, Wkb, (int)szW);
    to_bf16<<<dim3(512),  blk, 0, stream>>>(Wv, Wvb, (int)szW);

    detect_mask<<<dim3(1), blk, 0, stream>>>((const unsigned*)mask, mflag);
    const int words = NB * NS * NS / 64;
    pack_mask<<<dim3(words / 4), blk, 0, stream>>>(mask, mflag, mbits);

    dim3 g1(32, 8, 3);
    qkv_gemm<<<g1, blk, 0, stream>>>(xb, Wqb, bq, Wkb, bk, Wvb, bv, Qb, Kb, Vtb);

    dim3 g2(NS / 64, NH, NB);
    attn_kernel<<<g2, blk, 0, stream>>>(Qb, Kb, Vtb, mbits, out);
}